// Round 4
// baseline (625.540 us; speedup 1.0000x reference)
//
#include <hip/hip_runtime.h>
#include <math.h>

#define NN     1000000
#define NUPD   131072
#define HDIM   128
#define DMSG   256

#define GRU_ROWS    16
#define GRU_BLOCKS  (NUPD / GRU_ROWS)      // 8192
#define COPY_BLOCKS 8192
#define TOTAL_BLOCKS (GRU_BLOCKS + COPY_BLOCKS)
#define COPY_STRIDE  (COPY_BLOCKS * 256)   // 2,097,152 float4 / iter
#define COPY_ITERS   16                    // ceil(32,000,000 / 2,097,152) -> guarded
#define N4_TOTAL     ((long long)NN * (HDIM / 4))   // 32,000,000 float4

// ws layout: bf16 W_ih [384*256]; bf16 W_hh [384*128]; winner[NN]
#define WI_OFF  0
#define WH_OFF  (384 * 256 * 2)
#define WIN_OFF (WH_OFF + 384 * 128 * 2)

typedef __attribute__((ext_vector_type(8))) short bf16x8;
typedef __attribute__((ext_vector_type(4))) float f32x4;

__device__ __forceinline__ short f2bf(float f) {
  unsigned u = __float_as_uint(f);
  unsigned r = (u + 0x7fffu + ((u >> 16) & 1u)) >> 16;
  return (short)r;
}
__device__ __forceinline__ float sigmoidf_fast(float x) {
  return 1.0f / (1.0f + __expf(-x));
}
__device__ __forceinline__ float tanhf_fast(float x) {
  return 1.0f - 2.0f / (__expf(2.0f * x) + 1.0f);
}

// ---------------------------------------------------------------------------
// prep: winner marking (atomicMax, last-occurrence-wins) + f32->bf16 weights
// ---------------------------------------------------------------------------
__global__ void prep_kernel(const int* __restrict__ ids,
                            const float* __restrict__ Wi,
                            const float* __restrict__ Wh,
                            short* __restrict__ wi_bf,
                            short* __restrict__ wh_bf,
                            int* __restrict__ winner) {
  int i = blockIdx.x * 256 + threadIdx.x;
  if (i < NUPD) atomicMax(&winner[ids[i]], i);
  if (i < 384 * 256) wi_bf[i] = f2bf(Wi[i]);
  int j = i - 384 * 256;
  if (j >= 0 && j < 384 * 128) wh_bf[j] = f2bf(Wh[j]);
}

// ---------------------------------------------------------------------------
// Fat kernel, 256-thread blocks, even blockIdx = GRU tile (16 rows),
// odd blockIdx = copy slice (<=16 float4 per thread, winner rows skipped).
// ---------------------------------------------------------------------------
__launch_bounds__(256, 5)
__global__ void fat_kernel(const float* __restrict__ memory,
                           const int* __restrict__ node_ids,
                           const float* __restrict__ messages,
                           const short* __restrict__ Wi_bf,
                           const short* __restrict__ Wh_bf,
                           const float* __restrict__ b_ih,
                           const float* __restrict__ b_hh,
                           const int* __restrict__ winner,
                           float* __restrict__ out)
{
  __shared__ short xs[GRU_ROWS][DMSG + 8];   // bf16 x tile (+16B row skew)
  __shared__ short hs[GRU_ROWS][HDIM + 8];   // bf16 gathered h tile
  __shared__ int   ids_s[GRU_ROWS];
  __shared__ char  flag_s[GRU_ROWS];

  const int tid = threadIdx.x;

  if (blockIdx.x & 1) {
    // ---------------- copy path ----------------
    const int ci = blockIdx.x >> 1;                       // 0..8191
    const float4* __restrict__ src4 = (const float4*)memory;
    float4* __restrict__ dst4 = (float4*)out;
    const long long base = (long long)ci * 256 + tid;

    // preload winner flags (independent loads, guarded against N4_TOTAL)
    int w[COPY_ITERS];
#pragma unroll
    for (int it = 0; it < COPY_ITERS; ++it) {
      long long i = base + (long long)it * COPY_STRIDE;
      w[it] = (i < N4_TOTAL) ? winner[(int)(i >> 5)] : 0; // 32 float4 per row
    }
#pragma unroll
    for (int it = 0; it < COPY_ITERS; ++it) {
      long long i = base + (long long)it * COPY_STRIDE;
      if (i < N4_TOTAL && w[it] < 0) dst4[i] = src4[i];
    }
    return;
  }

  // ---------------- GRU path ----------------
  const int gi   = blockIdx.x >> 1;          // 0..8191
  const int row0 = gi * GRU_ROWS;
  const int lane = tid & 63;
  const int wv   = tid >> 6;                 // 0..3

  if (tid < GRU_ROWS) {
    int id = node_ids[row0 + tid];
    ids_s[tid] = id;
    flag_s[tid] = (winner[id] == row0 + tid) ? 1 : 0;
  }

  // stage x tile: 16 rows x 256 cols f32 -> bf16 (16 elems / thread)
  {
    int r = tid >> 4;            // 0..15
    int c16 = (tid & 15) * 16;
    const float4* p4 = (const float4*)(messages + (size_t)(row0 + r) * DMSG + c16);
    float4 v0 = p4[0], v1 = p4[1], v2 = p4[2], v3 = p4[3];
    bf16x8 o0, o1;
    o0[0] = f2bf(v0.x); o0[1] = f2bf(v0.y); o0[2] = f2bf(v0.z); o0[3] = f2bf(v0.w);
    o0[4] = f2bf(v1.x); o0[5] = f2bf(v1.y); o0[6] = f2bf(v1.z); o0[7] = f2bf(v1.w);
    o1[0] = f2bf(v2.x); o1[1] = f2bf(v2.y); o1[2] = f2bf(v2.z); o1[3] = f2bf(v2.w);
    o1[4] = f2bf(v3.x); o1[5] = f2bf(v3.y); o1[6] = f2bf(v3.z); o1[7] = f2bf(v3.w);
    *(bf16x8*)&xs[r][c16]     = o0;
    *(bf16x8*)&xs[r][c16 + 8] = o1;
  }

  // stage h tile: 16 rows x 128 cols gathered f32 -> bf16 (8 elems / thread)
  {
    int r = tid >> 4;            // 0..15
    int c8 = (tid & 15) * 8;
    int id = node_ids[row0 + r];
    const float4* p4 = (const float4*)(memory + (size_t)id * HDIM + c8);
    float4 v0 = p4[0], v1 = p4[1];
    bf16x8 o;
    o[0] = f2bf(v0.x); o[1] = f2bf(v0.y); o[2] = f2bf(v0.z); o[3] = f2bf(v0.w);
    o[4] = f2bf(v1.x); o[5] = f2bf(v1.y); o[6] = f2bf(v1.z); o[7] = f2bf(v1.w);
    *(bf16x8*)&hs[r][c8] = o;
  }

  __syncthreads();

  // wave wv owns output cols [wv*32, wv*32+32): two 16-col tiles c0,c1
  const int c0  = __builtin_amdgcn_readfirstlane(wv * 32);
  const int col = lane & 15;     // A row within tile / B col within col-tile
  const int kg  = lane >> 4;     // k-group

  f32x4 acc_r[2]  = {{0,0,0,0},{0,0,0,0}};
  f32x4 acc_z[2]  = {{0,0,0,0},{0,0,0,0}};
  f32x4 acc_in[2] = {{0,0,0,0},{0,0,0,0}};
  f32x4 acc_hn[2] = {{0,0,0,0},{0,0,0,0}};

  // ---- x part: K = 256 ----
#pragma unroll
  for (int ks = 0; ks < 8; ++ks) {
    const int ko = ks * 32 + kg * 8;
    bf16x8 a = *(const bf16x8*)&xs[col][ko];
#pragma unroll
    for (int ct = 0; ct < 2; ++ct) {
      const int g = c0 + ct * 16 + col;
      bf16x8 br = *(const bf16x8*)(Wi_bf + (size_t)(g)       * DMSG + ko);
      bf16x8 bz = *(const bf16x8*)(Wi_bf + (size_t)(g + 128) * DMSG + ko);
      bf16x8 bn = *(const bf16x8*)(Wi_bf + (size_t)(g + 256) * DMSG + ko);
      acc_r[ct]  = __builtin_amdgcn_mfma_f32_16x16x32_bf16(a, br, acc_r[ct], 0, 0, 0);
      acc_z[ct]  = __builtin_amdgcn_mfma_f32_16x16x32_bf16(a, bz, acc_z[ct], 0, 0, 0);
      acc_in[ct] = __builtin_amdgcn_mfma_f32_16x16x32_bf16(a, bn, acc_in[ct], 0, 0, 0);
    }
  }

  // ---- h part: K = 128 ----
#pragma unroll
  for (int ks = 0; ks < 4; ++ks) {
    const int ko = ks * 32 + kg * 8;
    bf16x8 a = *(const bf16x8*)&hs[col][ko];
#pragma unroll
    for (int ct = 0; ct < 2; ++ct) {
      const int g = c0 + ct * 16 + col;
      bf16x8 br = *(const bf16x8*)(Wh_bf + (size_t)(g)       * HDIM + ko);
      bf16x8 bz = *(const bf16x8*)(Wh_bf + (size_t)(g + 128) * HDIM + ko);
      bf16x8 bn = *(const bf16x8*)(Wh_bf + (size_t)(g + 256) * HDIM + ko);
      acc_r[ct]  = __builtin_amdgcn_mfma_f32_16x16x32_bf16(a, br, acc_r[ct], 0, 0, 0);
      acc_z[ct]  = __builtin_amdgcn_mfma_f32_16x16x32_bf16(a, bz, acc_z[ct], 0, 0, 0);
      acc_hn[ct] = __builtin_amdgcn_mfma_f32_16x16x32_bf16(a, bn, acc_hn[ct], 0, 0, 0);
    }
  }

  // ---- epilogue: gates + predicated scatter ----
#pragma unroll
  for (int ct = 0; ct < 2; ++ct) {
    const int g = c0 + ct * 16 + col;
    const float bias_r  = b_ih[g]       + b_hh[g];
    const float bias_z  = b_ih[g + 128] + b_hh[g + 128];
    const float bias_in = b_ih[g + 256];
    const float bias_hn = b_hh[g + 256];
#pragma unroll
    for (int reg = 0; reg < 4; ++reg) {
      const int row = kg * 4 + reg;              // C/D: row=(lane>>4)*4+reg
      const int id  = ids_s[row];
      float r = sigmoidf_fast(acc_r[ct][reg] + bias_r);
      float z = sigmoidf_fast(acc_z[ct][reg] + bias_z);
      float n = tanhf_fast(acc_in[ct][reg] + bias_in + r * (acc_hn[ct][reg] + bias_hn));
      float h = memory[(size_t)id * HDIM + g];
      float nh = (1.0f - z) * n + z * h;
      if (flag_s[row]) out[(size_t)id * HDIM + g] = nh;
    }
  }
}

extern "C" void kernel_launch(void* const* d_in, const int* in_sizes, int n_in,
                              void* d_out, int out_size, void* d_ws, size_t ws_size,
                              hipStream_t stream) {
  const float* memory   = (const float*)d_in[0];
  const int*   node_ids = (const int*)  d_in[1];
  const float* messages = (const float*)d_in[2];
  const float* W_ih     = (const float*)d_in[3];
  const float* W_hh     = (const float*)d_in[4];
  const float* b_ih     = (const float*)d_in[5];
  const float* b_hh     = (const float*)d_in[6];
  float* out = (float*)d_out;

  char* ws = (char*)d_ws;
  short* Wi_bf  = (short*)(ws + WI_OFF);
  short* Wh_bf  = (short*)(ws + WH_OFF);
  int*   winner = (int*)  (ws + WIN_OFF);

  hipMemsetAsync(winner, 0xFF, (size_t)NN * sizeof(int), stream);
  prep_kernel<<<(384 * 256 + 384 * 128 + 255) / 256, 256, 0, stream>>>(
      node_ids, W_ih, W_hh, Wi_bf, Wh_bf, winner);

  fat_kernel<<<TOTAL_BLOCKS, 256, 0, stream>>>(
      memory, node_ids, messages, Wi_bf, Wh_bf, b_ih, b_hh, winner, out);
}

// Round 5
// 359.883 us; speedup vs baseline: 1.7382x; 1.7382x over previous
//
#include <hip/hip_runtime.h>
#include <math.h>

#define NN     1000000
#define NUPD   131072
#define HDIM   128
#define DMSG   256

#define GRU_ROWS    32
#define GRU_BLOCKS  (NUPD / GRU_ROWS)      // 4096
#define COPY_BLOCKS 8192
#define TOTAL_BLOCKS (GRU_BLOCKS + COPY_BLOCKS)
#define COPY_STRIDE  ((long long)COPY_BLOCKS * 512)     // 4,194,304 float4 / iter
#define COPY_ITERS   8                                  // 8 * 4.19M = 33.5M >= 32M (guarded)
#define N4_TOTAL     ((long long)NN * (HDIM / 4))       // 32,000,000 float4

// ws layout: bf16 W_ih [384*256]; bf16 W_hh [384*128]; winner[NN]
#define WI_OFF  0
#define WH_OFF  (384 * 256 * 2)
#define WIN_OFF (WH_OFF + 384 * 128 * 2)

typedef __attribute__((ext_vector_type(8))) short bf16x8;
typedef __attribute__((ext_vector_type(4))) float f32x4;

__device__ __forceinline__ short f2bf(float f) {
  unsigned u = __float_as_uint(f);
  unsigned r = (u + 0x7fffu + ((u >> 16) & 1u)) >> 16;
  return (short)r;
}
__device__ __forceinline__ float sigmoidf_fast(float x) {
  return 1.0f / (1.0f + __expf(-x));
}
__device__ __forceinline__ float tanhf_fast(float x) {
  return 1.0f - 2.0f / (__expf(2.0f * x) + 1.0f);
}

// ---------------------------------------------------------------------------
// prep: winner marking (atomicMax, last-occurrence-wins) + f32->bf16 weights
// ---------------------------------------------------------------------------
__global__ void prep_kernel(const int* __restrict__ ids,
                            const float* __restrict__ Wi,
                            const float* __restrict__ Wh,
                            short* __restrict__ wi_bf,
                            short* __restrict__ wh_bf,
                            int* __restrict__ winner) {
  int i = blockIdx.x * 256 + threadIdx.x;
  if (i < NUPD) atomicMax(&winner[ids[i]], i);
  if (i < 384 * 256) wi_bf[i] = f2bf(Wi[i]);
  int j = i - 384 * 256;
  if (j >= 0 && j < 384 * 128) wh_bf[j] = f2bf(Wh[j]);
}

// ---------------------------------------------------------------------------
// Fat kernel, 512-thread blocks.
//  blocks [0, GRU_BLOCKS): GRU tile, 32 rows, 8 waves x 16-col band x 2 row-tiles.
//  blocks [GRU_BLOCKS, ...): copy slice, winner flags preloaded to registers.
// ---------------------------------------------------------------------------
__launch_bounds__(512, 6)
__global__ void fat_kernel(const float* __restrict__ memory,
                           const int* __restrict__ node_ids,
                           const float* __restrict__ messages,
                           const short* __restrict__ Wi_bf,
                           const short* __restrict__ Wh_bf,
                           const float* __restrict__ b_ih,
                           const float* __restrict__ b_hh,
                           const int* __restrict__ winner,
                           float* __restrict__ out)
{
  __shared__ short xs[GRU_ROWS][DMSG + 8];   // bf16 x tile (+16B row skew)
  __shared__ short hs[GRU_ROWS][HDIM + 8];   // bf16 gathered h tile
  __shared__ int   ids_s[GRU_ROWS];
  __shared__ char  flag_s[GRU_ROWS];

  const int tid = threadIdx.x;

  if (blockIdx.x >= GRU_BLOCKS) {
    // ---------------- copy path ----------------
    const int ci = blockIdx.x - GRU_BLOCKS;               // 0..COPY_BLOCKS-1
    const float4* __restrict__ src4 = (const float4*)memory;
    float4* __restrict__ dst4 = (float4*)out;
    const long long base = (long long)ci * 512 + tid;

    // independent winner preloads (breaks winner->load->store chain)
    int w[COPY_ITERS];
#pragma unroll
    for (int it = 0; it < COPY_ITERS; ++it) {
      long long i = base + (long long)it * COPY_STRIDE;
      w[it] = (i < N4_TOTAL) ? winner[(int)(i >> 5)] : 0; // 32 float4 per row
    }
#pragma unroll
    for (int it = 0; it < COPY_ITERS; ++it) {
      long long i = base + (long long)it * COPY_STRIDE;
      if (i < N4_TOTAL && w[it] < 0) dst4[i] = src4[i];
    }
    return;
  }

  // ---------------- GRU path ----------------
  const int row0 = blockIdx.x * GRU_ROWS;
  const int lane = tid & 63;
  const int wv   = tid >> 6;                 // 0..7

  if (tid < GRU_ROWS) {
    int id = node_ids[row0 + tid];
    ids_s[tid] = id;
    flag_s[tid] = (winner[id] == row0 + tid) ? 1 : 0;
  }

  // stage x tile: 32 rows x 256 cols f32 -> bf16 (16 elems / thread)
  {
    int r = tid >> 4;            // 0..31
    int c16 = (tid & 15) * 16;
    const float4* p4 = (const float4*)(messages + (size_t)(row0 + r) * DMSG + c16);
    float4 v0 = p4[0], v1 = p4[1], v2 = p4[2], v3 = p4[3];
    bf16x8 o0, o1;
    o0[0] = f2bf(v0.x); o0[1] = f2bf(v0.y); o0[2] = f2bf(v0.z); o0[3] = f2bf(v0.w);
    o0[4] = f2bf(v1.x); o0[5] = f2bf(v1.y); o0[6] = f2bf(v1.z); o0[7] = f2bf(v1.w);
    o1[0] = f2bf(v2.x); o1[1] = f2bf(v2.y); o1[2] = f2bf(v2.z); o1[3] = f2bf(v2.w);
    o1[4] = f2bf(v3.x); o1[5] = f2bf(v3.y); o1[6] = f2bf(v3.z); o1[7] = f2bf(v3.w);
    *(bf16x8*)&xs[r][c16]     = o0;
    *(bf16x8*)&xs[r][c16 + 8] = o1;
  }

  // stage h tile: 32 rows x 128 cols gathered f32 -> bf16 (8 elems / thread)
  {
    int r = tid >> 4;            // 0..31
    int c8 = (tid & 15) * 8;
    int id = node_ids[row0 + r];
    const float4* p4 = (const float4*)(memory + (size_t)id * HDIM + c8);
    float4 v0 = p4[0], v1 = p4[1];
    bf16x8 o;
    o[0] = f2bf(v0.x); o[1] = f2bf(v0.y); o[2] = f2bf(v0.z); o[3] = f2bf(v0.w);
    o[4] = f2bf(v1.x); o[5] = f2bf(v1.y); o[6] = f2bf(v1.z); o[7] = f2bf(v1.w);
    *(bf16x8*)&hs[r][c8] = o;
  }

  __syncthreads();

  // wave wv owns output cols [wv*16, wv*16+16), 2 row-tiles of 16
  const int g0  = __builtin_amdgcn_readfirstlane(wv * 16);
  const int col = lane & 15;     // A row within tile / B col
  const int kg  = lane >> 4;     // k-group
  const int g   = g0 + col;

  f32x4 acc_r[2]  = {{0,0,0,0},{0,0,0,0}};
  f32x4 acc_z[2]  = {{0,0,0,0},{0,0,0,0}};
  f32x4 acc_in[2] = {{0,0,0,0},{0,0,0,0}};
  f32x4 acc_hn[2] = {{0,0,0,0},{0,0,0,0}};

  // ---- x part: K = 256 (B-frags loaded once per ks, reused over 2 row-tiles) ----
#pragma unroll
  for (int ks = 0; ks < 8; ++ks) {
    const int ko = ks * 32 + kg * 8;
    bf16x8 br = *(const bf16x8*)(Wi_bf + (size_t)(g)       * DMSG + ko);
    bf16x8 bz = *(const bf16x8*)(Wi_bf + (size_t)(g + 128) * DMSG + ko);
    bf16x8 bn = *(const bf16x8*)(Wi_bf + (size_t)(g + 256) * DMSG + ko);
#pragma unroll
    for (int rt = 0; rt < 2; ++rt) {
      bf16x8 a = *(const bf16x8*)&xs[rt * 16 + col][ko];
      acc_r[rt]  = __builtin_amdgcn_mfma_f32_16x16x32_bf16(a, br, acc_r[rt], 0, 0, 0);
      acc_z[rt]  = __builtin_amdgcn_mfma_f32_16x16x32_bf16(a, bz, acc_z[rt], 0, 0, 0);
      acc_in[rt] = __builtin_amdgcn_mfma_f32_16x16x32_bf16(a, bn, acc_in[rt], 0, 0, 0);
    }
  }

  // ---- h part: K = 128 ----
#pragma unroll
  for (int ks = 0; ks < 4; ++ks) {
    const int ko = ks * 32 + kg * 8;
    bf16x8 br = *(const bf16x8*)(Wh_bf + (size_t)(g)       * HDIM + ko);
    bf16x8 bz = *(const bf16x8*)(Wh_bf + (size_t)(g + 128) * HDIM + ko);
    bf16x8 bn = *(const bf16x8*)(Wh_bf + (size_t)(g + 256) * HDIM + ko);
#pragma unroll
    for (int rt = 0; rt < 2; ++rt) {
      bf16x8 a = *(const bf16x8*)&hs[rt * 16 + col][ko];
      acc_r[rt]  = __builtin_amdgcn_mfma_f32_16x16x32_bf16(a, br, acc_r[rt], 0, 0, 0);
      acc_z[rt]  = __builtin_amdgcn_mfma_f32_16x16x32_bf16(a, bz, acc_z[rt], 0, 0, 0);
      acc_hn[rt] = __builtin_amdgcn_mfma_f32_16x16x32_bf16(a, bn, acc_hn[rt], 0, 0, 0);
    }
  }

  // ---- epilogue: gates + predicated scatter ----
  const float bias_r  = b_ih[g]       + b_hh[g];
  const float bias_z  = b_ih[g + 128] + b_hh[g + 128];
  const float bias_in = b_ih[g + 256];
  const float bias_hn = b_hh[g + 256];

#pragma unroll
  for (int rt = 0; rt < 2; ++rt) {
#pragma unroll
    for (int reg = 0; reg < 4; ++reg) {
      const int row = rt * 16 + kg * 4 + reg;    // C/D: row=(lane>>4)*4+reg
      const int id  = ids_s[row];
      float r = sigmoidf_fast(acc_r[rt][reg] + bias_r);
      float z = sigmoidf_fast(acc_z[rt][reg] + bias_z);
      float n = tanhf_fast(acc_in[rt][reg] + bias_in + r * (acc_hn[rt][reg] + bias_hn));
      float h = memory[(size_t)id * HDIM + g];
      float nh = (1.0f - z) * n + z * h;
      if (flag_s[row]) out[(size_t)id * HDIM + g] = nh;
    }
  }
}

extern "C" void kernel_launch(void* const* d_in, const int* in_sizes, int n_in,
                              void* d_out, int out_size, void* d_ws, size_t ws_size,
                              hipStream_t stream) {
  const float* memory   = (const float*)d_in[0];
  const int*   node_ids = (const int*)  d_in[1];
  const float* messages = (const float*)d_in[2];
  const float* W_ih     = (const float*)d_in[3];
  const float* W_hh     = (const float*)d_in[4];
  const float* b_ih     = (const float*)d_in[5];
  const float* b_hh     = (const float*)d_in[6];
  float* out = (float*)d_out;

  char* ws = (char*)d_ws;
  short* Wi_bf  = (short*)(ws + WI_OFF);
  short* Wh_bf  = (short*)(ws + WH_OFF);
  int*   winner = (int*)  (ws + WIN_OFF);

  hipMemsetAsync(winner, 0xFF, (size_t)NN * sizeof(int), stream);
  prep_kernel<<<(384 * 256 + 384 * 128 + 255) / 256, 256, 0, stream>>>(
      node_ids, W_ih, W_hh, Wi_bf, Wh_bf, winner);

  fat_kernel<<<TOTAL_BLOCKS, 512, 0, stream>>>(
      memory, node_ids, messages, Wi_bf, Wh_bf, b_ih, b_hh, winner, out);
}